// Round 1
// baseline (1440.871 us; speedup 1.0000x reference)
//
#include <hip/hip_runtime.h>
#include <math.h>

#define NPB 16           // nodes per block in GEMM
#define GEMM_THREADS 128

// Y[n][o] = norm[n] * sum_f feat[n][f] * W[o][f]
__global__ __launch_bounds__(GEMM_THREADS) void gemm_kernel(
    const float* __restrict__ feat, const float* __restrict__ norm,
    const float* __restrict__ W, float* __restrict__ Y, int n_nodes) {
  __shared__ float sWt[64][129];   // [f][o], +1 pad -> conflict-free
  __shared__ float sA[NPB][64];    // [node][f]
  const int o = threadIdx.x;       // output feature 0..127
  const int node0 = blockIdx.x * NPB;

  float acc[NPB];
#pragma unroll
  for (int n = 0; n < NPB; ++n) acc[n] = 0.f;

  for (int half = 0; half < 2; ++half) {
    __syncthreads();
    // stage W[:, half*64 : half*64+64] transposed into sWt[f][o]
#pragma unroll 4
    for (int k = 0; k < 64; ++k) {
      int e = k * GEMM_THREADS + o;    // 0..8191
      int oo = e >> 6;                 // 0..127
      int ff = e & 63;
      sWt[ff][oo] = W[oo * 128 + half * 64 + ff];
    }
    // stage feat rows for this block's nodes (this K-half)
#pragma unroll
    for (int k = 0; k < NPB / 2; ++k) {
      int e = k * GEMM_THREADS + o;    // 0..NPB*64-1
      int nn = e >> 6;
      int ff = e & 63;
      int node = node0 + nn;
      sA[nn][ff] = (node < n_nodes) ? feat[(size_t)node * 128 + half * 64 + ff] : 0.f;
    }
    __syncthreads();
#pragma unroll 4
    for (int f = 0; f < 64; ++f) {
      float w = sWt[f][o];
#pragma unroll
      for (int n = 0; n < NPB; ++n) acc[n] += sA[n][f] * w;
    }
  }
  // store with norm scaling
#pragma unroll
  for (int n = 0; n < NPB; ++n) {
    int node = node0 + n;
    if (node < n_nodes) Y[(size_t)node * 128 + o] = acc[n] * norm[node];
  }
}

// one 32-lane group per edge; float4 gather + 4 scalar atomic adds
__global__ __launch_bounds__(256) void scatter_kernel(
    const float* __restrict__ Y, const int* __restrict__ src,
    const int* __restrict__ dst, float* __restrict__ agg, int n_edges) {
  int e = blockIdx.x * (blockDim.x >> 5) + (threadIdx.x >> 5);
  if (e >= n_edges) return;
  int lane = threadIdx.x & 31;
  int s = src[e];
  int d = dst[e];
  float4 v = ((const float4*)(Y + (size_t)s * 128))[lane];
  float* out = agg + (size_t)d * 128 + lane * 4;
  atomicAdd(out + 0, v.x);
  atomicAdd(out + 1, v.y);
  atomicAdd(out + 2, v.z);
  atomicAdd(out + 3, v.w);
}

// out = tanh(norm * S + b), in place, float4-vectorized
__global__ __launch_bounds__(256) void finalize_kernel(
    float* __restrict__ out, const float* __restrict__ norm,
    const float* __restrict__ b, int n_nodes) {
  int idx = blockIdx.x * blockDim.x + threadIdx.x;  // one float4 each
  int total = n_nodes * 32;                          // 128 floats = 32 float4 per node
  if (idx >= total) return;
  int node = idx >> 5;
  int c4 = idx & 31;
  float nm = norm[node];
  float4 v = ((float4*)out)[idx];
  float4 bb = ((const float4*)b)[c4];
  v.x = tanhf(v.x * nm + bb.x);
  v.y = tanhf(v.y * nm + bb.y);
  v.z = tanhf(v.z * nm + bb.z);
  v.w = tanhf(v.w * nm + bb.w);
  ((float4*)out)[idx] = v;
}

extern "C" void kernel_launch(void* const* d_in, const int* in_sizes, int n_in,
                              void* d_out, int out_size, void* d_ws, size_t ws_size,
                              hipStream_t stream) {
  const float* feat = (const float*)d_in[0];   // [N,128]
  const float* norm = (const float*)d_in[1];   // [N,1]
  const float* W    = (const float*)d_in[2];   // [128,128]
  const float* b    = (const float*)d_in[3];   // [128]
  const int* src    = (const int*)d_in[4];     // [E]
  const int* dst    = (const int*)d_in[5];     // [E]
  float* out        = (float*)d_out;           // [N,128]

  const int n_nodes = in_sizes[1];
  const int n_edges = in_sizes[4];

  float* Y = (float*)d_ws;                     // [N,128] scratch

  // 1) Y = (feat * norm) @ W^T
  int gblocks = (n_nodes + NPB - 1) / NPB;
  gemm_kernel<<<gblocks, GEMM_THREADS, 0, stream>>>(feat, norm, W, Y, n_nodes);

  // 2) zero the aggregation buffer (d_out)
  hipMemsetAsync(d_out, 0, (size_t)out_size * sizeof(float), stream);

  // 3) scatter-add Y[src] into out[dst]
  int edges_per_block = 256 / 32;
  int sblocks = (n_edges + edges_per_block - 1) / edges_per_block;
  scatter_kernel<<<sblocks, 256, 0, stream>>>(Y, src, dst, out, n_edges);

  // 4) out = tanh(norm * out + b)
  int total4 = n_nodes * 32;
  int fblocks = (total4 + 255) / 256;
  finalize_kernel<<<fblocks, 256, 0, stream>>>(out, norm, b, n_nodes);
}

// Round 2
// 423.836 us; speedup vs baseline: 3.3996x; 3.3996x over previous
//
#include <hip/hip_runtime.h>
#include <math.h>

#define NPB 16           // nodes per block in GEMM
#define GEMM_THREADS 128

// Y[n][o] = norm[n] * sum_f feat[n][f] * W[o][f]
__global__ __launch_bounds__(GEMM_THREADS) void gemm_kernel(
    const float* __restrict__ feat, const float* __restrict__ norm,
    const float* __restrict__ W, float* __restrict__ Y, int n_nodes) {
  __shared__ float sWt[64][129];   // [f][o], +1 pad -> conflict-free
  __shared__ float sA[NPB][64];    // [node][f]
  const int o = threadIdx.x;       // output feature 0..127
  const int node0 = blockIdx.x * NPB;

  float acc[NPB];
#pragma unroll
  for (int n = 0; n < NPB; ++n) acc[n] = 0.f;

  for (int half = 0; half < 2; ++half) {
    __syncthreads();
#pragma unroll 4
    for (int k = 0; k < 64; ++k) {
      int e = k * GEMM_THREADS + o;    // 0..8191
      int oo = e >> 6;
      int ff = e & 63;
      sWt[ff][oo] = W[oo * 128 + half * 64 + ff];
    }
#pragma unroll
    for (int k = 0; k < NPB / 2; ++k) {
      int e = k * GEMM_THREADS + o;
      int nn = e >> 6;
      int ff = e & 63;
      int node = node0 + nn;
      sA[nn][ff] = (node < n_nodes) ? feat[(size_t)node * 128 + half * 64 + ff] : 0.f;
    }
    __syncthreads();
#pragma unroll 4
    for (int f = 0; f < 64; ++f) {
      float w = sWt[f][o];
#pragma unroll
      for (int n = 0; n < NPB; ++n) acc[n] += sA[n][f] * w;
    }
  }
#pragma unroll
  for (int n = 0; n < NPB; ++n) {
    int node = node0 + n;
    if (node < n_nodes) Y[(size_t)node * 128 + o] = acc[n] * norm[node];
  }
}

// histogram of dst
__global__ __launch_bounds__(256) void hist_kernel(
    const int* __restrict__ dst, int* __restrict__ counts, int n_edges) {
  for (int e = blockIdx.x * blockDim.x + threadIdx.x; e < n_edges;
       e += gridDim.x * blockDim.x) {
    atomicAdd(&counts[dst[e]], 1);
  }
}

// single-block exclusive scan: counts[0..n) -> row_start, cursor
__global__ __launch_bounds__(1024) void scan_kernel(
    const int* __restrict__ counts, int* __restrict__ row_start,
    int* __restrict__ cursor, int n) {
  __shared__ int s[1024];
  const int t = threadIdx.x;
  const int chunk = (n + 1023) / 1024;
  const int beg = t * chunk;
  const int end = min(beg + chunk, n);
  int sum = 0;
  for (int i = beg; i < end; ++i) sum += counts[i];
  s[t] = sum;
  __syncthreads();
  for (int off = 1; off < 1024; off <<= 1) {
    int v = (t >= off) ? s[t - off] : 0;
    __syncthreads();
    s[t] += v;
    __syncthreads();
  }
  int base = s[t] - sum;  // exclusive prefix
  for (int i = beg; i < end; ++i) {
    row_start[i] = base;
    cursor[i] = base;
    base += counts[i];
  }
}

// scatter src ids into dst-sorted order
__global__ __launch_bounds__(256) void scatter_ids_kernel(
    const int* __restrict__ src, const int* __restrict__ dst,
    int* __restrict__ cursor, int* __restrict__ sorted_src, int n_edges) {
  for (int e = blockIdx.x * blockDim.x + threadIdx.x; e < n_edges;
       e += gridDim.x * blockDim.x) {
    int d = dst[e];
    int pos = atomicAdd(&cursor[d], 1);
    sorted_src[pos] = src[e];
  }
}

// one 128-thread group per node: sum Y[src] rows, fused finalize
__global__ __launch_bounds__(256) void gather_kernel(
    const float* __restrict__ Y, const int* __restrict__ sorted_src,
    const int* __restrict__ row_start, const int* __restrict__ counts,
    const float* __restrict__ norm, const float* __restrict__ b,
    float* __restrict__ out, int n_nodes) {
  int node = blockIdx.x * 2 + (threadIdx.x >> 7);
  if (node >= n_nodes) return;
  int o = threadIdx.x & 127;
  int beg = row_start[node];
  int end = beg + counts[node];
  float acc = 0.f;
  for (int i = beg; i < end; ++i) {
    int s = sorted_src[i];
    acc += Y[(size_t)s * 128 + o];
  }
  float h = tanhf(acc * norm[node] + b[o]);
  out[(size_t)node * 128 + o] = h;
}

extern "C" void kernel_launch(void* const* d_in, const int* in_sizes, int n_in,
                              void* d_out, int out_size, void* d_ws, size_t ws_size,
                              hipStream_t stream) {
  const float* feat = (const float*)d_in[0];   // [N,128]
  const float* norm = (const float*)d_in[1];   // [N,1]
  const float* W    = (const float*)d_in[2];   // [128,128]
  const float* b    = (const float*)d_in[3];   // [128]
  const int* src    = (const int*)d_in[4];     // [E]
  const int* dst    = (const int*)d_in[5];     // [E]
  float* out        = (float*)d_out;           // [N,128]

  const int n_nodes = in_sizes[1];
  const int n_edges = in_sizes[4];

  // workspace layout
  char* base = (char*)d_ws;
  float* Y         = (float*)base;                         // N*128 f32
  size_t off = (size_t)n_nodes * 128 * sizeof(float);
  off = (off + 255) & ~(size_t)255;
  int* counts      = (int*)(base + off); off += (size_t)n_nodes * 4;
  off = (off + 255) & ~(size_t)255;
  int* row_start   = (int*)(base + off); off += (size_t)n_nodes * 4;
  off = (off + 255) & ~(size_t)255;
  int* cursor      = (int*)(base + off); off += (size_t)n_nodes * 4;
  off = (off + 255) & ~(size_t)255;
  int* sorted_src  = (int*)(base + off); off += (size_t)n_edges * 4;

  // 1) Y = (feat * norm) @ W^T
  int gblocks = (n_nodes + NPB - 1) / NPB;
  gemm_kernel<<<gblocks, GEMM_THREADS, 0, stream>>>(feat, norm, W, Y, n_nodes);

  // 2) histogram of dst
  hipMemsetAsync(counts, 0, (size_t)n_nodes * sizeof(int), stream);
  hist_kernel<<<2048, 256, 0, stream>>>(dst, counts, n_edges);

  // 3) exclusive scan -> CSR offsets
  scan_kernel<<<1, 1024, 0, stream>>>(counts, row_start, cursor, n_nodes);

  // 4) scatter src ids into dst-sorted order
  scatter_ids_kernel<<<2048, 256, 0, stream>>>(src, dst, cursor, sorted_src, n_edges);

  // 5) gather-reduce + fused tanh(norm*agg + b)
  int nblocks = (n_nodes + 1) / 2;
  gather_kernel<<<nblocks, 256, 0, stream>>>(Y, sorted_src, row_start, counts,
                                             norm, b, out, n_nodes);
}

// Round 3
// 292.378 us; speedup vs baseline: 4.9281x; 1.4496x over previous
//
#include <hip/hip_runtime.h>
#include <math.h>

// ---------------- GEMM: Y[n][o] = norm[n] * sum_f feat[n][f] * W[o][f] ----------------
// 256 threads, 64 nodes/block; thread computes 8 nodes x 4 outputs in registers.
__global__ __launch_bounds__(256) void gemm_kernel(
    const float* __restrict__ feat, const float* __restrict__ norm,
    const float* __restrict__ W, float* __restrict__ Y, int n_nodes) {
  __shared__ float sWt[64][132];   // [f][o] transposed; stride 132 words (16B aligned)
  __shared__ float sA[64][68];     // [node][f]; stride 68 words (16B aligned)
  const int t = threadIdx.x;
  const int node0 = blockIdx.x * 64;
  const int og = t & 31;           // outputs og*4 .. og*4+3
  const int ng = t >> 5;           // nodes ng*8 .. ng*8+7

  float acc[8][4];
#pragma unroll
  for (int j = 0; j < 8; ++j)
#pragma unroll
    for (int k = 0; k < 4; ++k) acc[j][k] = 0.f;

  for (int half = 0; half < 2; ++half) {
    __syncthreads();
    // stage W[:, half*64 .. +64] transposed: 8192 floats = 2048 float4
#pragma unroll
    for (int k = 0; k < 8; ++k) {
      int e4 = k * 256 + t;        // 0..2047
      int oo = e4 >> 4;            // 0..127
      int f4 = (e4 & 15) * 4;      // 0..60
      float4 w = *(const float4*)&W[oo * 128 + half * 64 + f4];
      sWt[f4 + 0][oo] = w.x; sWt[f4 + 1][oo] = w.y;
      sWt[f4 + 2][oo] = w.z; sWt[f4 + 3][oo] = w.w;
    }
    // stage feat rows: 64 nodes x 64 f = 1024 float4
#pragma unroll
    for (int k = 0; k < 4; ++k) {
      int e4 = k * 256 + t;        // 0..1023
      int nn = e4 >> 4;            // 0..63
      int f4 = (e4 & 15) * 4;
      int node = node0 + nn;
      float4 a = (node < n_nodes)
                     ? *(const float4*)&feat[(size_t)node * 128 + half * 64 + f4]
                     : make_float4(0.f, 0.f, 0.f, 0.f);
      *(float4*)&sA[nn][f4] = a;
    }
    __syncthreads();
#pragma unroll 4
    for (int f = 0; f < 64; ++f) {
      float4 w = *(const float4*)&sWt[f][og * 4];
#pragma unroll
      for (int j = 0; j < 8; ++j) {
        float a = sA[ng * 8 + j][f];
        acc[j][0] += a * w.x; acc[j][1] += a * w.y;
        acc[j][2] += a * w.z; acc[j][3] += a * w.w;
      }
    }
  }
#pragma unroll
  for (int j = 0; j < 8; ++j) {
    int node = node0 + ng * 8 + j;
    if (node < n_nodes) {
      float nm = norm[node];
      float4 v = make_float4(acc[j][0] * nm, acc[j][1] * nm,
                             acc[j][2] * nm, acc[j][3] * nm);
      *(float4*)&Y[(size_t)node * 128 + og * 4] = v;
    }
  }
}

// ---------------- histogram of dst (int4 loads) ----------------
__global__ __launch_bounds__(256) void hist_kernel(
    const int* __restrict__ dst, int* __restrict__ counts, int n_edges) {
  int n4 = n_edges >> 2;
  for (int i = blockIdx.x * blockDim.x + threadIdx.x; i < n4;
       i += gridDim.x * blockDim.x) {
    int4 d = ((const int4*)dst)[i];
    atomicAdd(&counts[d.x], 1);
    atomicAdd(&counts[d.y], 1);
    atomicAdd(&counts[d.z], 1);
    atomicAdd(&counts[d.w], 1);
  }
  // tail
  int tail0 = n4 << 2;
  int idx = blockIdx.x * blockDim.x + threadIdx.x;
  if (idx < n_edges - tail0) atomicAdd(&counts[dst[tail0 + idx]], 1);
}

// ---------------- single-block exclusive scan ----------------
__global__ __launch_bounds__(1024) void scan_kernel(
    const int* __restrict__ counts, int* __restrict__ row_start,
    int* __restrict__ cursor, int n) {
  __shared__ int s[1024];
  const int t = threadIdx.x;
  const int chunk = (n + 1023) / 1024;
  const int beg = t * chunk;
  const int end = min(beg + chunk, n);
  int sum = 0;
  for (int i = beg; i < end; ++i) sum += counts[i];
  s[t] = sum;
  __syncthreads();
  for (int off = 1; off < 1024; off <<= 1) {
    int v = (t >= off) ? s[t - off] : 0;
    __syncthreads();
    s[t] += v;
    __syncthreads();
  }
  int base = s[t] - sum;  // exclusive prefix
  for (int i = beg; i < end; ++i) {
    row_start[i] = base;
    cursor[i] = base;
    base += counts[i];
  }
}

// ---------------- scatter src ids into dst-sorted order ----------------
__global__ __launch_bounds__(256) void scatter_ids_kernel(
    const int* __restrict__ src, const int* __restrict__ dst,
    int* __restrict__ cursor, int* __restrict__ sorted_src, int n_edges) {
  int n4 = n_edges >> 2;
  for (int i = blockIdx.x * blockDim.x + threadIdx.x; i < n4;
       i += gridDim.x * blockDim.x) {
    int4 s = ((const int4*)src)[i];
    int4 d = ((const int4*)dst)[i];
    sorted_src[atomicAdd(&cursor[d.x], 1)] = s.x;
    sorted_src[atomicAdd(&cursor[d.y], 1)] = s.y;
    sorted_src[atomicAdd(&cursor[d.z], 1)] = s.z;
    sorted_src[atomicAdd(&cursor[d.w], 1)] = s.w;
  }
  int tail0 = n4 << 2;
  int idx = blockIdx.x * blockDim.x + threadIdx.x;
  if (idx < n_edges - tail0) {
    int e = tail0 + idx;
    sorted_src[atomicAdd(&cursor[dst[e]], 1)] = src[e];
  }
}

// ---------------- gather-reduce + fused tanh ----------------
// one 64-lane wave per node; float2 per lane covers the full 512B row
__global__ __launch_bounds__(256) void gather_kernel(
    const float* __restrict__ Y, const int* __restrict__ sorted_src,
    const int* __restrict__ row_start, const int* __restrict__ counts,
    const float* __restrict__ norm, const float* __restrict__ b,
    float* __restrict__ out, int n_nodes) {
  int node = blockIdx.x * 4 + (threadIdx.x >> 6);
  if (node >= n_nodes) return;
  int lane = threadIdx.x & 63;
  int beg = row_start[node];
  int cnt = counts[node];
  const float2* Y2 = (const float2*)Y;
  float accx = 0.f, accy = 0.f;
  int i = beg, end = beg + cnt;
  for (; i + 4 <= end; i += 4) {
    int s0 = sorted_src[i + 0];
    int s1 = sorted_src[i + 1];
    int s2 = sorted_src[i + 2];
    int s3 = sorted_src[i + 3];
    float2 v0 = Y2[(size_t)s0 * 64 + lane];
    float2 v1 = Y2[(size_t)s1 * 64 + lane];
    float2 v2 = Y2[(size_t)s2 * 64 + lane];
    float2 v3 = Y2[(size_t)s3 * 64 + lane];
    accx += v0.x + v1.x + v2.x + v3.x;
    accy += v0.y + v1.y + v2.y + v3.y;
  }
  for (; i < end; ++i) {
    int s = sorted_src[i];
    float2 v = Y2[(size_t)s * 64 + lane];
    accx += v.x;
    accy += v.y;
  }
  float nm = norm[node];
  float2 bb = ((const float2*)b)[lane];
  float2 h;
  h.x = tanhf(accx * nm + bb.x);
  h.y = tanhf(accy * nm + bb.y);
  ((float2*)out)[(size_t)node * 64 + lane] = h;
}

extern "C" void kernel_launch(void* const* d_in, const int* in_sizes, int n_in,
                              void* d_out, int out_size, void* d_ws, size_t ws_size,
                              hipStream_t stream) {
  const float* feat = (const float*)d_in[0];   // [N,128]
  const float* norm = (const float*)d_in[1];   // [N,1]
  const float* W    = (const float*)d_in[2];   // [128,128]
  const float* b    = (const float*)d_in[3];   // [128]
  const int* src    = (const int*)d_in[4];     // [E]
  const int* dst    = (const int*)d_in[5];     // [E]
  float* out        = (float*)d_out;           // [N,128]

  const int n_nodes = in_sizes[1];
  const int n_edges = in_sizes[4];

  // workspace layout
  char* base = (char*)d_ws;
  float* Y         = (float*)base;
  size_t off = (size_t)n_nodes * 128 * sizeof(float);
  off = (off + 255) & ~(size_t)255;
  int* counts      = (int*)(base + off); off += (size_t)n_nodes * 4;
  off = (off + 255) & ~(size_t)255;
  int* row_start   = (int*)(base + off); off += (size_t)n_nodes * 4;
  off = (off + 255) & ~(size_t)255;
  int* cursor      = (int*)(base + off); off += (size_t)n_nodes * 4;
  off = (off + 255) & ~(size_t)255;
  int* sorted_src  = (int*)(base + off); off += (size_t)n_edges * 4;

  // 1) Y = (feat * norm) @ W^T
  int gblocks = (n_nodes + 63) / 64;
  gemm_kernel<<<gblocks, 256, 0, stream>>>(feat, norm, W, Y, n_nodes);

  // 2) histogram of dst
  hipMemsetAsync(counts, 0, (size_t)n_nodes * sizeof(int), stream);
  hist_kernel<<<1024, 256, 0, stream>>>(dst, counts, n_edges);

  // 3) exclusive scan -> CSR offsets
  scan_kernel<<<1, 1024, 0, stream>>>(counts, row_start, cursor, n_nodes);

  // 4) scatter src ids into dst-sorted order
  scatter_ids_kernel<<<1024, 256, 0, stream>>>(src, dst, cursor, sorted_src, n_edges);

  // 5) gather-reduce + fused tanh(norm*agg + b)
  int nblocks = (n_nodes + 3) / 4;
  gather_kernel<<<nblocks, 256, 0, stream>>>(Y, sorted_src, row_start, counts,
                                             norm, b, out, n_nodes);
}

// Round 4
// 193.085 us; speedup vs baseline: 7.4624x; 1.5142x over previous
//
#include <hip/hip_runtime.h>
#include <math.h>

// ---------------- GEMM: Y[n][o] = norm[n] * sum_f feat[n][f] * W[o][f] ----------------
// 256 threads, 64 nodes/block; thread computes 8 nodes x 4 outputs in registers.
__global__ __launch_bounds__(256) void gemm_kernel(
    const float* __restrict__ feat, const float* __restrict__ norm,
    const float* __restrict__ W, float* __restrict__ Y, int n_nodes) {
  __shared__ float sWt[64][132];   // [f][o] transposed
  __shared__ float sA[64][68];     // [node][f]
  const int t = threadIdx.x;
  const int node0 = blockIdx.x * 64;
  const int og = t & 31;
  const int ng = t >> 5;

  float acc[8][4];
#pragma unroll
  for (int j = 0; j < 8; ++j)
#pragma unroll
    for (int k = 0; k < 4; ++k) acc[j][k] = 0.f;

  for (int half = 0; half < 2; ++half) {
    __syncthreads();
#pragma unroll
    for (int k = 0; k < 8; ++k) {
      int e4 = k * 256 + t;
      int oo = e4 >> 4;
      int f4 = (e4 & 15) * 4;
      float4 w = *(const float4*)&W[oo * 128 + half * 64 + f4];
      sWt[f4 + 0][oo] = w.x; sWt[f4 + 1][oo] = w.y;
      sWt[f4 + 2][oo] = w.z; sWt[f4 + 3][oo] = w.w;
    }
#pragma unroll
    for (int k = 0; k < 4; ++k) {
      int e4 = k * 256 + t;
      int nn = e4 >> 4;
      int f4 = (e4 & 15) * 4;
      int node = node0 + nn;
      float4 a = (node < n_nodes)
                     ? *(const float4*)&feat[(size_t)node * 128 + half * 64 + f4]
                     : make_float4(0.f, 0.f, 0.f, 0.f);
      *(float4*)&sA[nn][f4] = a;
    }
    __syncthreads();
#pragma unroll 4
    for (int f = 0; f < 64; ++f) {
      float4 w = *(const float4*)&sWt[f][og * 4];
#pragma unroll
      for (int j = 0; j < 8; ++j) {
        float a = sA[ng * 8 + j][f];
        acc[j][0] += a * w.x; acc[j][1] += a * w.y;
        acc[j][2] += a * w.z; acc[j][3] += a * w.w;
      }
    }
  }
#pragma unroll
  for (int j = 0; j < 8; ++j) {
    int node = node0 + ng * 8 + j;
    if (node < n_nodes) {
      float nm = norm[node];
      float4 v = make_float4(acc[j][0] * nm, acc[j][1] * nm,
                             acc[j][2] * nm, acc[j][3] * nm);
      *(float4*)&Y[(size_t)node * 128 + og * 4] = v;
    }
  }
}

// ---------------- histogram of dst (int4 loads) ----------------
__global__ __launch_bounds__(256) void hist_kernel(
    const int* __restrict__ dst, int* __restrict__ counts, int n_edges) {
  int n4 = n_edges >> 2;
  for (int i = blockIdx.x * blockDim.x + threadIdx.x; i < n4;
       i += gridDim.x * blockDim.x) {
    int4 d = ((const int4*)dst)[i];
    atomicAdd(&counts[d.x], 1);
    atomicAdd(&counts[d.y], 1);
    atomicAdd(&counts[d.z], 1);
    atomicAdd(&counts[d.w], 1);
  }
  int tail0 = n4 << 2;
  int idx = blockIdx.x * blockDim.x + threadIdx.x;
  if (idx < n_edges - tail0) atomicAdd(&counts[dst[tail0 + idx]], 1);
}

// ---------------- device-wide scan, 3 phases ----------------
#define SCAN_BLOCK 256
#define SCAN_ITEMS 4   // 1024 elements per block

// phase 1: per-block exclusive prefix -> row_start (local), block totals
__global__ __launch_bounds__(SCAN_BLOCK) void scan1_kernel(
    const int* __restrict__ counts, int* __restrict__ row_start,
    int* __restrict__ blockSums, int n) {
  __shared__ int s[SCAN_BLOCK];
  int t = threadIdx.x;
  int base = blockIdx.x * (SCAN_BLOCK * SCAN_ITEMS) + t * SCAN_ITEMS;
  int v[SCAN_ITEMS];
#pragma unroll
  for (int j = 0; j < SCAN_ITEMS; ++j) v[j] = (base + j < n) ? counts[base + j] : 0;
  int tsum = v[0] + v[1] + v[2] + v[3];
  s[t] = tsum;
  __syncthreads();
  for (int off = 1; off < SCAN_BLOCK; off <<= 1) {
    int u = (t >= off) ? s[t - off] : 0;
    __syncthreads();
    s[t] += u;
    __syncthreads();
  }
  int texcl = s[t] - tsum;
  if (t == SCAN_BLOCK - 1) blockSums[blockIdx.x] = s[t];
  int run = texcl;
#pragma unroll
  for (int j = 0; j < SCAN_ITEMS; ++j) {
    if (base + j < n) row_start[base + j] = run;
    run += v[j];
  }
}

// phase 2: single small block scans block sums (nb <= 256)
__global__ __launch_bounds__(SCAN_BLOCK) void scan2_kernel(
    int* __restrict__ blockSums, int nb) {
  __shared__ int s[SCAN_BLOCK];
  int t = threadIdx.x;
  int v = (t < nb) ? blockSums[t] : 0;
  s[t] = v;
  __syncthreads();
  for (int off = 1; off < SCAN_BLOCK; off <<= 1) {
    int u = (t >= off) ? s[t - off] : 0;
    __syncthreads();
    s[t] += u;
    __syncthreads();
  }
  if (t < nb) blockSums[t] = s[t] - v;  // exclusive
}

// phase 3: add block offsets; mirror into cursor
__global__ __launch_bounds__(SCAN_BLOCK) void scan3_kernel(
    int* __restrict__ row_start, int* __restrict__ cursor,
    const int* __restrict__ blockSums, int n) {
  int t = threadIdx.x;
  int base = blockIdx.x * (SCAN_BLOCK * SCAN_ITEMS) + t * SCAN_ITEMS;
  int off = blockSums[blockIdx.x];
#pragma unroll
  for (int j = 0; j < SCAN_ITEMS; ++j) {
    int i = base + j;
    if (i < n) {
      int r = row_start[i] + off;
      row_start[i] = r;
      cursor[i] = r;
    }
  }
}

// ---------------- scatter src ids into dst-sorted order ----------------
__global__ __launch_bounds__(256) void scatter_ids_kernel(
    const int* __restrict__ src, const int* __restrict__ dst,
    int* __restrict__ cursor, int* __restrict__ sorted_src, int n_edges) {
  int n4 = n_edges >> 2;
  for (int i = blockIdx.x * blockDim.x + threadIdx.x; i < n4;
       i += gridDim.x * blockDim.x) {
    int4 s = ((const int4*)src)[i];
    int4 d = ((const int4*)dst)[i];
    sorted_src[atomicAdd(&cursor[d.x], 1)] = s.x;
    sorted_src[atomicAdd(&cursor[d.y], 1)] = s.y;
    sorted_src[atomicAdd(&cursor[d.z], 1)] = s.z;
    sorted_src[atomicAdd(&cursor[d.w], 1)] = s.w;
  }
  int tail0 = n4 << 2;
  int idx = blockIdx.x * blockDim.x + threadIdx.x;
  if (idx < n_edges - tail0) {
    int e = tail0 + idx;
    sorted_src[atomicAdd(&cursor[dst[e]], 1)] = src[e];
  }
}

// ---------------- gather-reduce + fused tanh ----------------
// one 64-lane wave per node; float2 per lane covers the full 512B row
__global__ __launch_bounds__(256) void gather_kernel(
    const float* __restrict__ Y, const int* __restrict__ sorted_src,
    const int* __restrict__ row_start, const int* __restrict__ counts,
    const float* __restrict__ norm, const float* __restrict__ b,
    float* __restrict__ out, int n_nodes) {
  int node = blockIdx.x * 4 + (threadIdx.x >> 6);
  if (node >= n_nodes) return;
  int lane = threadIdx.x & 63;
  int beg = row_start[node];
  int cnt = counts[node];
  const float2* Y2 = (const float2*)Y;
  float accx = 0.f, accy = 0.f;
  int i = beg, end = beg + cnt;
  for (; i + 4 <= end; i += 4) {
    int s0 = sorted_src[i + 0];
    int s1 = sorted_src[i + 1];
    int s2 = sorted_src[i + 2];
    int s3 = sorted_src[i + 3];
    float2 v0 = Y2[(size_t)s0 * 64 + lane];
    float2 v1 = Y2[(size_t)s1 * 64 + lane];
    float2 v2 = Y2[(size_t)s2 * 64 + lane];
    float2 v3 = Y2[(size_t)s3 * 64 + lane];
    accx += v0.x + v1.x + v2.x + v3.x;
    accy += v0.y + v1.y + v2.y + v3.y;
  }
  for (; i < end; ++i) {
    int s = sorted_src[i];
    float2 v = Y2[(size_t)s * 64 + lane];
    accx += v.x;
    accy += v.y;
  }
  float nm = norm[node];
  float2 bb = ((const float2*)b)[lane];
  float2 h;
  h.x = tanhf(accx * nm + bb.x);
  h.y = tanhf(accy * nm + bb.y);
  ((float2*)out)[(size_t)node * 64 + lane] = h;
}

extern "C" void kernel_launch(void* const* d_in, const int* in_sizes, int n_in,
                              void* d_out, int out_size, void* d_ws, size_t ws_size,
                              hipStream_t stream) {
  const float* feat = (const float*)d_in[0];   // [N,128]
  const float* norm = (const float*)d_in[1];   // [N,1]
  const float* W    = (const float*)d_in[2];   // [128,128]
  const float* b    = (const float*)d_in[3];   // [128]
  const int* src    = (const int*)d_in[4];     // [E]
  const int* dst    = (const int*)d_in[5];     // [E]
  float* out        = (float*)d_out;           // [N,128]

  const int n_nodes = in_sizes[1];
  const int n_edges = in_sizes[4];

  // workspace layout
  char* base = (char*)d_ws;
  float* Y         = (float*)base;
  size_t off = (size_t)n_nodes * 128 * sizeof(float);
  off = (off + 255) & ~(size_t)255;
  int* counts      = (int*)(base + off); off += (size_t)n_nodes * 4;
  off = (off + 255) & ~(size_t)255;
  int* row_start   = (int*)(base + off); off += (size_t)n_nodes * 4;
  off = (off + 255) & ~(size_t)255;
  int* cursor      = (int*)(base + off); off += (size_t)n_nodes * 4;
  off = (off + 255) & ~(size_t)255;
  int* sorted_src  = (int*)(base + off); off += (size_t)n_edges * 4;
  off = (off + 255) & ~(size_t)255;
  int* blockSums   = (int*)(base + off); off += 1024 * 4;

  // 1) Y = (feat * norm) @ W^T
  int gblocks = (n_nodes + 63) / 64;
  gemm_kernel<<<gblocks, 256, 0, stream>>>(feat, norm, W, Y, n_nodes);

  // 2) histogram of dst
  hipMemsetAsync(counts, 0, (size_t)n_nodes * sizeof(int), stream);
  hist_kernel<<<1024, 256, 0, stream>>>(dst, counts, n_edges);

  // 3) device-wide exclusive scan -> CSR offsets
  int elems_per_blk = SCAN_BLOCK * SCAN_ITEMS;
  int nb = (n_nodes + elems_per_blk - 1) / elems_per_blk;   // 49 for N=50000
  scan1_kernel<<<nb, SCAN_BLOCK, 0, stream>>>(counts, row_start, blockSums, n_nodes);
  scan2_kernel<<<1, SCAN_BLOCK, 0, stream>>>(blockSums, nb);
  scan3_kernel<<<nb, SCAN_BLOCK, 0, stream>>>(row_start, cursor, blockSums, n_nodes);

  // 4) scatter src ids into dst-sorted order
  scatter_ids_kernel<<<1024, 256, 0, stream>>>(src, dst, cursor, sorted_src, n_edges);

  // 5) gather-reduce + fused tanh(norm*agg + b)
  int nblocks = (n_nodes + 3) / 4;
  gather_kernel<<<nblocks, 256, 0, stream>>>(Y, sorted_src, row_start, counts,
                                             norm, b, out, n_nodes);
}

// Round 5
// 190.434 us; speedup vs baseline: 7.5663x; 1.0139x over previous
//
#include <hip/hip_runtime.h>
#include <math.h>

#define PAD 16   // ints per 64B cacheline: one counter per line

// ---------------- GEMM: Y[n][o] = norm[n] * sum_f feat[n][f] * W[o][f] ----------------
__global__ __launch_bounds__(256) void gemm_kernel(
    const float* __restrict__ feat, const float* __restrict__ norm,
    const float* __restrict__ W, float* __restrict__ Y, int n_nodes) {
  __shared__ float sWt[64][132];   // [f][o] transposed
  __shared__ float sA[64][68];     // [node][f]
  const int t = threadIdx.x;
  const int node0 = blockIdx.x * 64;
  const int og = t & 31;
  const int ng = t >> 5;

  float acc[8][4];
#pragma unroll
  for (int j = 0; j < 8; ++j)
#pragma unroll
    for (int k = 0; k < 4; ++k) acc[j][k] = 0.f;

  for (int half = 0; half < 2; ++half) {
    __syncthreads();
#pragma unroll
    for (int k = 0; k < 8; ++k) {
      int e4 = k * 256 + t;
      int oo = e4 >> 4;
      int f4 = (e4 & 15) * 4;
      float4 w = *(const float4*)&W[oo * 128 + half * 64 + f4];
      sWt[f4 + 0][oo] = w.x; sWt[f4 + 1][oo] = w.y;
      sWt[f4 + 2][oo] = w.z; sWt[f4 + 3][oo] = w.w;
    }
#pragma unroll
    for (int k = 0; k < 4; ++k) {
      int e4 = k * 256 + t;
      int nn = e4 >> 4;
      int f4 = (e4 & 15) * 4;
      int node = node0 + nn;
      float4 a = (node < n_nodes)
                     ? *(const float4*)&feat[(size_t)node * 128 + half * 64 + f4]
                     : make_float4(0.f, 0.f, 0.f, 0.f);
      *(float4*)&sA[nn][f4] = a;
    }
    __syncthreads();
#pragma unroll 4
    for (int f = 0; f < 64; ++f) {
      float4 w = *(const float4*)&sWt[f][og * 4];
#pragma unroll
      for (int j = 0; j < 8; ++j) {
        float a = sA[ng * 8 + j][f];
        acc[j][0] += a * w.x; acc[j][1] += a * w.y;
        acc[j][2] += a * w.z; acc[j][3] += a * w.w;
      }
    }
  }
#pragma unroll
  for (int j = 0; j < 8; ++j) {
    int node = node0 + ng * 8 + j;
    if (node < n_nodes) {
      float nm = norm[node];
      float4 v = make_float4(acc[j][0] * nm, acc[j][1] * nm,
                             acc[j][2] * nm, acc[j][3] * nm);
      *(float4*)&Y[(size_t)node * 128 + og * 4] = v;
    }
  }
}

// ---------------- histogram of dst into PADDED counters ----------------
__global__ __launch_bounds__(256) void hist_kernel(
    const int* __restrict__ dst, int* __restrict__ counts_p, int n_edges) {
  int n4 = n_edges >> 2;
  for (int i = blockIdx.x * blockDim.x + threadIdx.x; i < n4;
       i += gridDim.x * blockDim.x) {
    int4 d = ((const int4*)dst)[i];
    atomicAdd(&counts_p[(size_t)d.x * PAD], 1);
    atomicAdd(&counts_p[(size_t)d.y * PAD], 1);
    atomicAdd(&counts_p[(size_t)d.z * PAD], 1);
    atomicAdd(&counts_p[(size_t)d.w * PAD], 1);
  }
  int tail0 = n4 << 2;
  int idx = blockIdx.x * blockDim.x + threadIdx.x;
  if (idx < n_edges - tail0)
    atomicAdd(&counts_p[(size_t)dst[tail0 + idx] * PAD], 1);
}

// ---------------- device-wide scan, 3 phases ----------------
#define SCAN_BLOCK 256
#define SCAN_ITEMS 4   // 1024 elements per block

// phase 1: read padded counts -> dense counts_d, per-block exclusive prefix, block totals
__global__ __launch_bounds__(SCAN_BLOCK) void scan1_kernel(
    const int* __restrict__ counts_p, int* __restrict__ counts_d,
    int* __restrict__ row_start, int* __restrict__ blockSums, int n) {
  __shared__ int s[SCAN_BLOCK];
  int t = threadIdx.x;
  int base = blockIdx.x * (SCAN_BLOCK * SCAN_ITEMS) + t * SCAN_ITEMS;
  int v[SCAN_ITEMS];
#pragma unroll
  for (int j = 0; j < SCAN_ITEMS; ++j)
    v[j] = (base + j < n) ? counts_p[(size_t)(base + j) * PAD] : 0;
  int tsum = v[0] + v[1] + v[2] + v[3];
  s[t] = tsum;
  __syncthreads();
  for (int off = 1; off < SCAN_BLOCK; off <<= 1) {
    int u = (t >= off) ? s[t - off] : 0;
    __syncthreads();
    s[t] += u;
    __syncthreads();
  }
  int texcl = s[t] - tsum;
  if (t == SCAN_BLOCK - 1) blockSums[blockIdx.x] = s[t];
  int run = texcl;
#pragma unroll
  for (int j = 0; j < SCAN_ITEMS; ++j) {
    if (base + j < n) {
      counts_d[base + j] = v[j];
      row_start[base + j] = run;
    }
    run += v[j];
  }
}

// phase 2: single small block scans block sums (nb <= 256)
__global__ __launch_bounds__(SCAN_BLOCK) void scan2_kernel(
    int* __restrict__ blockSums, int nb) {
  __shared__ int s[SCAN_BLOCK];
  int t = threadIdx.x;
  int v = (t < nb) ? blockSums[t] : 0;
  s[t] = v;
  __syncthreads();
  for (int off = 1; off < SCAN_BLOCK; off <<= 1) {
    int u = (t >= off) ? s[t - off] : 0;
    __syncthreads();
    s[t] += u;
    __syncthreads();
  }
  if (t < nb) blockSums[t] = s[t] - v;  // exclusive
}

// phase 3: add block offsets to dense row_start; init PADDED cursor
__global__ __launch_bounds__(SCAN_BLOCK) void scan3_kernel(
    int* __restrict__ row_start, int* __restrict__ cursor_p,
    const int* __restrict__ blockSums, int n) {
  int t = threadIdx.x;
  int base = blockIdx.x * (SCAN_BLOCK * SCAN_ITEMS) + t * SCAN_ITEMS;
  int off = blockSums[blockIdx.x];
#pragma unroll
  for (int j = 0; j < SCAN_ITEMS; ++j) {
    int i = base + j;
    if (i < n) {
      int r = row_start[i] + off;
      row_start[i] = r;
      cursor_p[(size_t)i * PAD] = r;
    }
  }
}

// ---------------- scatter src ids into dst-sorted order (padded cursor) ----------------
__global__ __launch_bounds__(256) void scatter_ids_kernel(
    const int* __restrict__ src, const int* __restrict__ dst,
    int* __restrict__ cursor_p, int* __restrict__ sorted_src, int n_edges) {
  int n4 = n_edges >> 2;
  for (int i = blockIdx.x * blockDim.x + threadIdx.x; i < n4;
       i += gridDim.x * blockDim.x) {
    int4 s = ((const int4*)src)[i];
    int4 d = ((const int4*)dst)[i];
    sorted_src[atomicAdd(&cursor_p[(size_t)d.x * PAD], 1)] = s.x;
    sorted_src[atomicAdd(&cursor_p[(size_t)d.y * PAD], 1)] = s.y;
    sorted_src[atomicAdd(&cursor_p[(size_t)d.z * PAD], 1)] = s.z;
    sorted_src[atomicAdd(&cursor_p[(size_t)d.w * PAD], 1)] = s.w;
  }
  int tail0 = n4 << 2;
  int idx = blockIdx.x * blockDim.x + threadIdx.x;
  if (idx < n_edges - tail0) {
    int e = tail0 + idx;
    sorted_src[atomicAdd(&cursor_p[(size_t)dst[e] * PAD], 1)] = src[e];
  }
}

// ---------------- gather-reduce + fused tanh ----------------
// one 64-lane wave per node; float2 per lane covers the full 512B row; unroll 8
__global__ __launch_bounds__(256) void gather_kernel(
    const float* __restrict__ Y, const int* __restrict__ sorted_src,
    const int* __restrict__ row_start, const int* __restrict__ counts_d,
    const float* __restrict__ norm, const float* __restrict__ b,
    float* __restrict__ out, int n_nodes) {
  int node = blockIdx.x * 4 + (threadIdx.x >> 6);
  if (node >= n_nodes) return;
  int lane = threadIdx.x & 63;
  int beg = row_start[node];
  int cnt = counts_d[node];
  const float2* Y2 = (const float2*)Y;
  float accx = 0.f, accy = 0.f;
  int i = beg, end = beg + cnt;
  for (; i + 8 <= end; i += 8) {
    int s0 = sorted_src[i + 0];
    int s1 = sorted_src[i + 1];
    int s2 = sorted_src[i + 2];
    int s3 = sorted_src[i + 3];
    int s4 = sorted_src[i + 4];
    int s5 = sorted_src[i + 5];
    int s6 = sorted_src[i + 6];
    int s7 = sorted_src[i + 7];
    float2 v0 = Y2[(size_t)s0 * 64 + lane];
    float2 v1 = Y2[(size_t)s1 * 64 + lane];
    float2 v2 = Y2[(size_t)s2 * 64 + lane];
    float2 v3 = Y2[(size_t)s3 * 64 + lane];
    float2 v4 = Y2[(size_t)s4 * 64 + lane];
    float2 v5 = Y2[(size_t)s5 * 64 + lane];
    float2 v6 = Y2[(size_t)s6 * 64 + lane];
    float2 v7 = Y2[(size_t)s7 * 64 + lane];
    accx += (v0.x + v1.x) + (v2.x + v3.x) + ((v4.x + v5.x) + (v6.x + v7.x));
    accy += (v0.y + v1.y) + (v2.y + v3.y) + ((v4.y + v5.y) + (v6.y + v7.y));
  }
  for (; i + 4 <= end; i += 4) {
    int s0 = sorted_src[i + 0];
    int s1 = sorted_src[i + 1];
    int s2 = sorted_src[i + 2];
    int s3 = sorted_src[i + 3];
    float2 v0 = Y2[(size_t)s0 * 64 + lane];
    float2 v1 = Y2[(size_t)s1 * 64 + lane];
    float2 v2 = Y2[(size_t)s2 * 64 + lane];
    float2 v3 = Y2[(size_t)s3 * 64 + lane];
    accx += (v0.x + v1.x) + (v2.x + v3.x);
    accy += (v0.y + v1.y) + (v2.y + v3.y);
  }
  for (; i < end; ++i) {
    int s = sorted_src[i];
    float2 v = Y2[(size_t)s * 64 + lane];
    accx += v.x;
    accy += v.y;
  }
  float nm = norm[node];
  float2 bb = ((const float2*)b)[lane];
  float2 h;
  h.x = tanhf(accx * nm + bb.x);
  h.y = tanhf(accy * nm + bb.y);
  ((float2*)out)[(size_t)node * 64 + lane] = h;
}

extern "C" void kernel_launch(void* const* d_in, const int* in_sizes, int n_in,
                              void* d_out, int out_size, void* d_ws, size_t ws_size,
                              hipStream_t stream) {
  const float* feat = (const float*)d_in[0];   // [N,128]
  const float* norm = (const float*)d_in[1];   // [N,1]
  const float* W    = (const float*)d_in[2];   // [128,128]
  const float* b    = (const float*)d_in[3];   // [128]
  const int* src    = (const int*)d_in[4];     // [E]
  const int* dst    = (const int*)d_in[5];     // [E]
  float* out        = (float*)d_out;           // [N,128]

  const int n_nodes = in_sizes[1];
  const int n_edges = in_sizes[4];

  // workspace layout
  char* base = (char*)d_ws;
  float* Y         = (float*)base;                                    // N*128 f32
  size_t off = (size_t)n_nodes * 128 * sizeof(float);
  off = (off + 255) & ~(size_t)255;
  int* counts_p    = (int*)(base + off); off += (size_t)n_nodes * PAD * 4;  // padded counts -> reused as cursor
  off = (off + 255) & ~(size_t)255;
  int* counts_d    = (int*)(base + off); off += (size_t)n_nodes * 4;  // dense
  off = (off + 255) & ~(size_t)255;
  int* row_start   = (int*)(base + off); off += (size_t)n_nodes * 4;  // dense
  off = (off + 255) & ~(size_t)255;
  int* sorted_src  = (int*)(base + off); off += (size_t)n_edges * 4;
  off = (off + 255) & ~(size_t)255;
  int* blockSums   = (int*)(base + off); off += 1024 * 4;

  // 1) Y = (feat * norm) @ W^T
  int gblocks = (n_nodes + 63) / 64;
  gemm_kernel<<<gblocks, 256, 0, stream>>>(feat, norm, W, Y, n_nodes);

  // 2) histogram of dst (padded counters: 1 per 64B line)
  hipMemsetAsync(counts_p, 0, (size_t)n_nodes * PAD * sizeof(int), stream);
  hist_kernel<<<1024, 256, 0, stream>>>(dst, counts_p, n_edges);

  // 3) device-wide exclusive scan -> dense row_start/counts, padded cursor
  int elems_per_blk = SCAN_BLOCK * SCAN_ITEMS;
  int nb = (n_nodes + elems_per_blk - 1) / elems_per_blk;   // 49 for N=50000
  scan1_kernel<<<nb, SCAN_BLOCK, 0, stream>>>(counts_p, counts_d, row_start, blockSums, n_nodes);
  scan2_kernel<<<1, SCAN_BLOCK, 0, stream>>>(blockSums, nb);
  scan3_kernel<<<nb, SCAN_BLOCK, 0, stream>>>(row_start, counts_p, blockSums, n_nodes);

  // 4) scatter src ids into dst-sorted order
  scatter_ids_kernel<<<1024, 256, 0, stream>>>(src, dst, counts_p, sorted_src, n_edges);

  // 5) gather-reduce + fused tanh(norm*agg + b)
  int nblocks = (n_nodes + 3) / 4;
  gather_kernel<<<nblocks, 256, 0, stream>>>(Y, sorted_src, row_start, counts_d,
                                             norm, b, out, n_nodes);
}